// Round 1
// baseline (1003.646 us; speedup 1.0000x reference)
//
#include <hip/hip_runtime.h>

#define NN 100000
#define EE 1600000
#define CH 128
#define NG 512
#define OC 64

// workspace element offsets (4-byte units); total ~111 MB
#define O_DINV   0
#define O_DEG    100096
#define O_ROWS   200128
#define O_CURS   300160
#define O_PART   400192
#define O_OFFS   400320
#define O_CSR    400448
#define O_HS     2000448
#define O_A1     14800448
#define O_POOL   27600448
#define O_CNT    27665984
#define O_G1     27666496

__global__ void k_deg(const int* __restrict__ dst, int* __restrict__ deg) {
  int e = blockIdx.x * 256 + threadIdx.x;
  if (e < EE) atomicAdd(&deg[dst[e]], 1);
}

__global__ void k_dinv(const int* __restrict__ deg, float* __restrict__ dinv) {
  int i = blockIdx.x * 256 + threadIdx.x;
  if (i < NN) dinv[i] = rsqrtf((float)(deg[i] + 1));  // +1 self-loop
}

__global__ __launch_bounds__(1024) void k_scan_block(const int* __restrict__ deg,
                                                     int* __restrict__ rows,
                                                     int* __restrict__ part) {
  __shared__ int s[1024];
  int t = threadIdx.x;
  int gid = blockIdx.x * 1024 + t;
  int v = (gid < NN) ? deg[gid] : 0;
  s[t] = v;
  __syncthreads();
  for (int off = 1; off < 1024; off <<= 1) {
    int u = (t >= off) ? s[t - off] : 0;
    __syncthreads();
    if (t >= off) s[t] += u;
    __syncthreads();
  }
  if (gid < NN) rows[gid] = s[t] - v;       // exclusive
  if (t == 1023) part[blockIdx.x] = s[t];   // block total
}

__global__ void k_scan_part(const int* __restrict__ part, int* __restrict__ offs) {
  __shared__ int s[128];
  int t = threadIdx.x;
  int v = (t < 98) ? part[t] : 0;
  s[t] = v;
  __syncthreads();
  for (int off = 1; off < 128; off <<= 1) {
    int u = (t >= off) ? s[t - off] : 0;
    __syncthreads();
    if (t >= off) s[t] += u;
    __syncthreads();
  }
  if (t < 98) offs[t] = s[t] - v;
}

__global__ void k_scan_add(int* __restrict__ rows, const int* __restrict__ offs) {
  int i = blockIdx.x * 256 + threadIdx.x;
  if (i < NN) rows[i] += offs[i >> 10];
  if (i == 0) rows[NN] = EE;
}

__global__ void k_fill(const int* __restrict__ src, const int* __restrict__ dst,
                       const int* __restrict__ rows, int* __restrict__ curs,
                       int* __restrict__ csr) {
  int e = blockIdx.x * 256 + threadIdx.x;
  if (e < EE) {
    int d = dst[e];
    int pos = atomicAdd(&curs[d], 1);
    csr[rows[d] + pos] = src[e];
  }
}

// Hs = diag(dinv) * (X @ W).  64-row tile, 256 threads, 4x8 register tile.
__global__ __launch_bounds__(256) void k_gemm_scale(
    const float* __restrict__ X, const float* __restrict__ W,
    const float* __restrict__ dinv, float* __restrict__ Hs) {
  __shared__ float Xs[64][36];   // stride 36: 16B-aligned float4 stores, 2-way banks (free)
  __shared__ float Ws[32][128];
  const int t = threadIdx.x;
  const int tx = t & 15;   // 16 col groups * 8 cols
  const int ty = t >> 4;   // 16 row groups * 4 rows
  const int row0 = blockIdx.x * 64;
  float acc[4][8];
#pragma unroll
  for (int i = 0; i < 4; ++i)
#pragma unroll
    for (int j = 0; j < 8; ++j) acc[i][j] = 0.f;

  const int lr = t >> 2;          // 0..63 staging row
  const int lk = (t & 3) * 8;     // 0,8,16,24
  const int wk = t >> 5;          // 0..7
  const int wc = (t & 31) * 4;

  for (int kc = 0; kc < 128; kc += 32) {
    if (row0 + lr < NN) {
      const float* xp = X + (size_t)(row0 + lr) * CH + kc + lk;
      *(float4*)&Xs[lr][lk] = *(const float4*)xp;
      *(float4*)&Xs[lr][lk + 4] = *(const float4*)(xp + 4);
    } else {
      float4 z = {0.f, 0.f, 0.f, 0.f};
      *(float4*)&Xs[lr][lk] = z;
      *(float4*)&Xs[lr][lk + 4] = z;
    }
#pragma unroll
    for (int i = 0; i < 4; ++i)
      *(float4*)&Ws[wk + 8 * i][wc] =
          *(const float4*)(W + (size_t)(kc + wk + 8 * i) * CH + wc);
    __syncthreads();
#pragma unroll
    for (int k = 0; k < 32; ++k) {
      float4 w0 = *(float4*)&Ws[k][tx * 8];
      float4 w1 = *(float4*)&Ws[k][tx * 8 + 4];
#pragma unroll
      for (int i = 0; i < 4; ++i) {
        float xv = Xs[ty * 4 + i][k];
        acc[i][0] += xv * w0.x; acc[i][1] += xv * w0.y;
        acc[i][2] += xv * w0.z; acc[i][3] += xv * w0.w;
        acc[i][4] += xv * w1.x; acc[i][5] += xv * w1.y;
        acc[i][6] += xv * w1.z; acc[i][7] += xv * w1.w;
      }
    }
    __syncthreads();
  }
#pragma unroll
  for (int i = 0; i < 4; ++i) {
    int r = row0 + ty * 4 + i;
    if (r < NN) {
      float d = dinv[r];
      float4 o0 = {d * acc[i][0], d * acc[i][1], d * acc[i][2], d * acc[i][3]};
      float4 o1 = {d * acc[i][4], d * acc[i][5], d * acc[i][6], d * acc[i][7]};
      float* hp = Hs + (size_t)r * CH + tx * 8;
      *(float4*)hp = o0;
      *(float4*)(hp + 4) = o1;
    }
  }
}

// out[i] = relu(dinv[i]*(Hs[i] + sum_{e:dst=i} Hs[csr[e]]) + b). One wave per node.
__global__ __launch_bounds__(256) void k_aggregate(
    const float* __restrict__ Hs, const int* __restrict__ rows,
    const int* __restrict__ csr, const float* __restrict__ dinv,
    const float* __restrict__ bias, float* __restrict__ out) {
  int node = blockIdx.x * 4 + (threadIdx.x >> 6);
  int lane = threadIdx.x & 63;
  if (node >= NN) return;
  const float2* H2 = (const float2*)Hs;
  float2 a = H2[(size_t)node * 64 + lane];  // self-loop term
  float ax = a.x, ay = a.y;
  int e0 = rows[node], e1 = rows[node + 1];
  for (int e = e0; e < e1; ++e) {
    int j = csr[e];
    float2 v = H2[(size_t)j * 64 + lane];
    ax += v.x;
    ay += v.y;
  }
  float d = dinv[node];
  float bx = bias[2 * lane], by = bias[2 * lane + 1];
  float2 o;
  o.x = fmaxf(fmaf(d, ax, bx), 0.f);
  o.y = fmaxf(fmaf(d, ay, by), 0.f);
  ((float2*)out)[(size_t)node * 64 + lane] = o;
}

__global__ void k_pool(const float* __restrict__ A, const int* __restrict__ batch,
                       float* __restrict__ sums, float* __restrict__ cnt) {
  int node = blockIdx.x * 2 + (threadIdx.x >> 7);
  int c = threadIdx.x & 127;
  if (node >= NN) return;
  int g = batch[node];
  atomicAdd(&sums[(size_t)g * CH + c], A[(size_t)node * CH + c]);
  if (c == 0) atomicAdd(&cnt[g], 1.0f);
}

__global__ void k_head1(const float* __restrict__ sums, const float* __restrict__ cnt,
                        const float* __restrict__ W3, const float* __restrict__ b3,
                        float* __restrict__ g1) {
  __shared__ float row[128];
  int g = blockIdx.x, c = threadIdx.x;
  float n = fmaxf(cnt[g], 1.0f);
  row[c] = sums[(size_t)g * CH + c] / n;
  __syncthreads();
  float acc = b3[c];
  for (int k = 0; k < 128; ++k) acc += row[k] * W3[(size_t)k * CH + c];
  g1[(size_t)g * CH + c] = fmaxf(acc, 0.f);
}

__global__ void k_head2(const float* __restrict__ g1, const float* __restrict__ W4,
                        const float* __restrict__ b4, float* __restrict__ out) {
  __shared__ float row[128];
  int g = blockIdx.x, c = threadIdx.x;  // 64 threads
  row[c] = g1[(size_t)g * CH + c];
  row[c + 64] = g1[(size_t)g * CH + c + 64];
  __syncthreads();
  float acc = b4[c];
  for (int k = 0; k < 128; ++k) acc += row[k] * W4[(size_t)k * OC + c];
  out[(size_t)g * OC + c] = acc;
}

extern "C" void kernel_launch(void* const* d_in, const int* in_sizes, int n_in,
                              void* d_out, int out_size, void* d_ws, size_t ws_size,
                              hipStream_t stream) {
  const float* X   = (const float*)d_in[0];
  const int* ei    = (const int*)d_in[1];
  const int* batch = (const int*)d_in[2];
  const float* W1  = (const float*)d_in[3];
  const float* b1  = (const float*)d_in[4];
  const float* W2  = (const float*)d_in[5];
  const float* b2  = (const float*)d_in[6];
  const float* W3  = (const float*)d_in[7];
  const float* b3  = (const float*)d_in[8];
  const float* W4  = (const float*)d_in[9];
  const float* b4  = (const float*)d_in[10];
  float* out = (float*)d_out;
  float* ws = (float*)d_ws;

  const int* src = ei;        // edge_index[0]
  const int* dst = ei + EE;   // edge_index[1]

  float* dinv = ws + O_DINV;
  int* deg    = (int*)(ws + O_DEG);
  int* rows   = (int*)(ws + O_ROWS);
  int* curs   = (int*)(ws + O_CURS);
  int* part   = (int*)(ws + O_PART);
  int* offs   = (int*)(ws + O_OFFS);
  int* csr    = (int*)(ws + O_CSR);
  float* Hs   = ws + O_HS;
  float* A1   = ws + O_A1;
  float* pool = ws + O_POOL;
  float* cnt  = ws + O_CNT;   // contiguous after pool
  float* g1   = ws + O_G1;

  hipMemsetAsync(deg, 0, NN * sizeof(int), stream);
  hipMemsetAsync(curs, 0, NN * sizeof(int), stream);
  hipMemsetAsync(pool, 0, (NG * CH + NG) * sizeof(float), stream);  // pool + cnt

  k_deg<<<(EE + 255) / 256, 256, 0, stream>>>(dst, deg);
  k_dinv<<<(NN + 255) / 256, 256, 0, stream>>>(deg, dinv);
  k_scan_block<<<98, 1024, 0, stream>>>(deg, rows, part);
  k_scan_part<<<1, 128, 0, stream>>>(part, offs);
  k_scan_add<<<(NN + 255) / 256, 256, 0, stream>>>(rows, offs);
  k_fill<<<(EE + 255) / 256, 256, 0, stream>>>(src, dst, rows, curs, csr);

  // layer 1
  k_gemm_scale<<<(NN + 63) / 64, 256, 0, stream>>>(X, W1, dinv, Hs);
  k_aggregate<<<(NN + 3) / 4, 256, 0, stream>>>(Hs, rows, csr, dinv, b1, A1);
  // layer 2 (reuse buffers)
  k_gemm_scale<<<(NN + 63) / 64, 256, 0, stream>>>(A1, W2, dinv, Hs);
  k_aggregate<<<(NN + 3) / 4, 256, 0, stream>>>(Hs, rows, csr, dinv, b2, A1);

  k_pool<<<(NN + 1) / 2, 256, 0, stream>>>(A1, batch, pool, cnt);
  k_head1<<<NG, 128, 0, stream>>>(pool, cnt, W3, b3, g1);
  k_head2<<<NG, 64, 0, stream>>>(g1, W4, b4, out);
}

// Round 2
// 734.771 us; speedup vs baseline: 1.3659x; 1.3659x over previous
//
#include <hip/hip_runtime.h>

#define NN 100000
#define EE 1600000
#define CH 128
#define NG 512
#define OC 64

// workspace element offsets (4-byte units); total ~111 MB
#define O_DINV   0
#define O_DEG    100096
#define O_ROWS   200128
#define O_CURS   300160
#define O_PART   400192
#define O_OFFS   400320
#define O_CSR    400448
#define O_HS     2000448
#define O_A1     14800448
#define O_START  27600448
#define O_POOL   27601024
#define O_G1     27666560

__global__ void k_deg(const int* __restrict__ dst, int* __restrict__ deg) {
  int e = blockIdx.x * 256 + threadIdx.x;
  if (e < EE) atomicAdd(&deg[dst[e]], 1);
}

__global__ void k_dinv(const int* __restrict__ deg, float* __restrict__ dinv) {
  int i = blockIdx.x * 256 + threadIdx.x;
  if (i < NN) dinv[i] = rsqrtf((float)(deg[i] + 1));  // +1 self-loop
}

__global__ __launch_bounds__(1024) void k_scan_block(const int* __restrict__ deg,
                                                     int* __restrict__ rows,
                                                     int* __restrict__ part) {
  __shared__ int s[1024];
  int t = threadIdx.x;
  int gid = blockIdx.x * 1024 + t;
  int v = (gid < NN) ? deg[gid] : 0;
  s[t] = v;
  __syncthreads();
  for (int off = 1; off < 1024; off <<= 1) {
    int u = (t >= off) ? s[t - off] : 0;
    __syncthreads();
    if (t >= off) s[t] += u;
    __syncthreads();
  }
  if (gid < NN) rows[gid] = s[t] - v;       // exclusive
  if (t == 1023) part[blockIdx.x] = s[t];   // block total
}

__global__ void k_scan_part(const int* __restrict__ part, int* __restrict__ offs) {
  __shared__ int s[128];
  int t = threadIdx.x;
  int v = (t < 98) ? part[t] : 0;
  s[t] = v;
  __syncthreads();
  for (int off = 1; off < 128; off <<= 1) {
    int u = (t >= off) ? s[t - off] : 0;
    __syncthreads();
    if (t >= off) s[t] += u;
    __syncthreads();
  }
  if (t < 98) offs[t] = s[t] - v;
}

__global__ void k_scan_add(int* __restrict__ rows, const int* __restrict__ offs) {
  int i = blockIdx.x * 256 + threadIdx.x;
  if (i < NN) rows[i] += offs[i >> 10];
  if (i == 0) rows[NN] = EE;
}

__global__ void k_fill(const int* __restrict__ src, const int* __restrict__ dst,
                       const int* __restrict__ rows, int* __restrict__ curs,
                       int* __restrict__ csr) {
  int e = blockIdx.x * 256 + threadIdx.x;
  if (e < EE) {
    int d = dst[e];
    int pos = atomicAdd(&curs[d], 1);
    csr[rows[d] + pos] = src[e];
  }
}

// Hs = diag(dinv) * (X @ W).  64-row tile, 256 threads, 4x8 register tile.
__global__ __launch_bounds__(256) void k_gemm_scale(
    const float* __restrict__ X, const float* __restrict__ W,
    const float* __restrict__ dinv, float* __restrict__ Hs) {
  __shared__ float Xs[64][36];   // stride 36: 16B-aligned float4 stores, 2-way banks (free)
  __shared__ float Ws[32][128];
  const int t = threadIdx.x;
  const int tx = t & 15;   // 16 col groups * 8 cols
  const int ty = t >> 4;   // 16 row groups * 4 rows
  const int row0 = blockIdx.x * 64;
  float acc[4][8];
#pragma unroll
  for (int i = 0; i < 4; ++i)
#pragma unroll
    for (int j = 0; j < 8; ++j) acc[i][j] = 0.f;

  const int lr = t >> 2;          // 0..63 staging row
  const int lk = (t & 3) * 8;     // 0,8,16,24
  const int wk = t >> 5;          // 0..7
  const int wc = (t & 31) * 4;

  for (int kc = 0; kc < 128; kc += 32) {
    if (row0 + lr < NN) {
      const float* xp = X + (size_t)(row0 + lr) * CH + kc + lk;
      *(float4*)&Xs[lr][lk] = *(const float4*)xp;
      *(float4*)&Xs[lr][lk + 4] = *(const float4*)(xp + 4);
    } else {
      float4 z = {0.f, 0.f, 0.f, 0.f};
      *(float4*)&Xs[lr][lk] = z;
      *(float4*)&Xs[lr][lk + 4] = z;
    }
#pragma unroll
    for (int i = 0; i < 4; ++i)
      *(float4*)&Ws[wk + 8 * i][wc] =
          *(const float4*)(W + (size_t)(kc + wk + 8 * i) * CH + wc);
    __syncthreads();
#pragma unroll
    for (int k = 0; k < 32; ++k) {
      float4 w0 = *(float4*)&Ws[k][tx * 8];
      float4 w1 = *(float4*)&Ws[k][tx * 8 + 4];
#pragma unroll
      for (int i = 0; i < 4; ++i) {
        float xv = Xs[ty * 4 + i][k];
        acc[i][0] += xv * w0.x; acc[i][1] += xv * w0.y;
        acc[i][2] += xv * w0.z; acc[i][3] += xv * w0.w;
        acc[i][4] += xv * w1.x; acc[i][5] += xv * w1.y;
        acc[i][6] += xv * w1.z; acc[i][7] += xv * w1.w;
      }
    }
    __syncthreads();
  }
#pragma unroll
  for (int i = 0; i < 4; ++i) {
    int r = row0 + ty * 4 + i;
    if (r < NN) {
      float d = dinv[r];
      float4 o0 = {d * acc[i][0], d * acc[i][1], d * acc[i][2], d * acc[i][3]};
      float4 o1 = {d * acc[i][4], d * acc[i][5], d * acc[i][6], d * acc[i][7]};
      float* hp = Hs + (size_t)r * CH + tx * 8;
      *(float4*)hp = o0;
      *(float4*)(hp + 4) = o1;
    }
  }
}

// out[i] = relu(dinv[i]*(Hs[i] + sum_{e:dst=i} Hs[csr[e]]) + b). One wave per node.
__global__ __launch_bounds__(256) void k_aggregate(
    const float* __restrict__ Hs, const int* __restrict__ rows,
    const int* __restrict__ csr, const float* __restrict__ dinv,
    const float* __restrict__ bias, float* __restrict__ out) {
  int node = blockIdx.x * 4 + (threadIdx.x >> 6);
  int lane = threadIdx.x & 63;
  if (node >= NN) return;
  const float2* H2 = (const float2*)Hs;
  float2 a = H2[(size_t)node * 64 + lane];  // self-loop term
  float ax = a.x, ay = a.y;
  int e0 = rows[node], e1 = rows[node + 1];
  for (int e = e0; e < e1; ++e) {
    int j = csr[e];
    float2 v = H2[(size_t)j * 64 + lane];
    ax += v.x;
    ay += v.y;
  }
  float d = dinv[node];
  float bx = bias[2 * lane], by = bias[2 * lane + 1];
  float2 o;
  o.x = fmaxf(fmaf(d, ax, bx), 0.f);
  o.y = fmaxf(fmaf(d, ay, by), 0.f);
  ((float2*)out)[(size_t)node * 64 + lane] = o;
}

// batch is sorted: graph g occupies nodes [start[g], start[g+1]).
__global__ void k_starts(const int* __restrict__ batch, int* __restrict__ start) {
  int i = blockIdx.x * 256 + threadIdx.x;
  if (i >= NN) return;
  int b = batch[i];
  int prev = (i == 0) ? -1 : batch[i - 1];
  for (int g = prev + 1; g <= b; ++g) start[g] = i;
  if (i == NN - 1)
    for (int g = b + 1; g <= NG; ++g) start[g] = NN;
}

// one block (2 waves) per graph: segmented mean, no atomics.
__global__ __launch_bounds__(256) void k_pool_mean(
    const float* __restrict__ A, const int* __restrict__ start,
    float* __restrict__ pooled) {
  __shared__ float part[128];
  int g = blockIdx.x;
  int c = threadIdx.x & 127;
  int half = threadIdx.x >> 7;
  int s0 = start[g], s1 = start[g + 1];
  float sum = 0.f;
  for (int i = s0 + half; i < s1; i += 2)
    sum += A[(size_t)i * CH + c];
  if (half) part[c] = sum;
  __syncthreads();
  if (!half) {
    sum += part[c];
    float n = fmaxf((float)(s1 - s0), 1.0f);
    pooled[(size_t)g * CH + c] = sum / n;
  }
}

__global__ void k_head1(const float* __restrict__ pooled,
                        const float* __restrict__ W3, const float* __restrict__ b3,
                        float* __restrict__ g1) {
  __shared__ float row[128];
  int g = blockIdx.x, c = threadIdx.x;
  row[c] = pooled[(size_t)g * CH + c];
  __syncthreads();
  float acc = b3[c];
  for (int k = 0; k < 128; ++k) acc += row[k] * W3[(size_t)k * CH + c];
  g1[(size_t)g * CH + c] = fmaxf(acc, 0.f);
}

__global__ void k_head2(const float* __restrict__ g1, const float* __restrict__ W4,
                        const float* __restrict__ b4, float* __restrict__ out) {
  __shared__ float row[128];
  int g = blockIdx.x, c = threadIdx.x;  // 64 threads
  row[c] = g1[(size_t)g * CH + c];
  row[c + 64] = g1[(size_t)g * CH + c + 64];
  __syncthreads();
  float acc = b4[c];
  for (int k = 0; k < 128; ++k) acc += row[k] * W4[(size_t)k * OC + c];
  out[(size_t)g * OC + c] = acc;
}

extern "C" void kernel_launch(void* const* d_in, const int* in_sizes, int n_in,
                              void* d_out, int out_size, void* d_ws, size_t ws_size,
                              hipStream_t stream) {
  const float* X   = (const float*)d_in[0];
  const int* ei    = (const int*)d_in[1];
  const int* batch = (const int*)d_in[2];
  const float* W1  = (const float*)d_in[3];
  const float* b1  = (const float*)d_in[4];
  const float* W2  = (const float*)d_in[5];
  const float* b2  = (const float*)d_in[6];
  const float* W3  = (const float*)d_in[7];
  const float* b3  = (const float*)d_in[8];
  const float* W4  = (const float*)d_in[9];
  const float* b4  = (const float*)d_in[10];
  float* out = (float*)d_out;
  float* ws = (float*)d_ws;

  const int* src = ei;        // edge_index[0]
  const int* dst = ei + EE;   // edge_index[1]

  float* dinv = ws + O_DINV;
  int* deg    = (int*)(ws + O_DEG);
  int* rows   = (int*)(ws + O_ROWS);
  int* curs   = (int*)(ws + O_CURS);
  int* part   = (int*)(ws + O_PART);
  int* offs   = (int*)(ws + O_OFFS);
  int* csr    = (int*)(ws + O_CSR);
  float* Hs   = ws + O_HS;
  float* A1   = ws + O_A1;
  int* start  = (int*)(ws + O_START);
  float* pool = ws + O_POOL;
  float* g1   = ws + O_G1;

  hipMemsetAsync(deg, 0, NN * sizeof(int), stream);
  hipMemsetAsync(curs, 0, NN * sizeof(int), stream);

  k_deg<<<(EE + 255) / 256, 256, 0, stream>>>(dst, deg);
  k_dinv<<<(NN + 255) / 256, 256, 0, stream>>>(deg, dinv);
  k_scan_block<<<98, 1024, 0, stream>>>(deg, rows, part);
  k_scan_part<<<1, 128, 0, stream>>>(part, offs);
  k_scan_add<<<(NN + 255) / 256, 256, 0, stream>>>(rows, offs);
  k_fill<<<(EE + 255) / 256, 256, 0, stream>>>(src, dst, rows, curs, csr);
  k_starts<<<(NN + 255) / 256, 256, 0, stream>>>(batch, start);

  // layer 1
  k_gemm_scale<<<(NN + 63) / 64, 256, 0, stream>>>(X, W1, dinv, Hs);
  k_aggregate<<<(NN + 3) / 4, 256, 0, stream>>>(Hs, rows, csr, dinv, b1, A1);
  // layer 2 (reuse buffers)
  k_gemm_scale<<<(NN + 63) / 64, 256, 0, stream>>>(A1, W2, dinv, Hs);
  k_aggregate<<<(NN + 3) / 4, 256, 0, stream>>>(Hs, rows, csr, dinv, b2, A1);

  k_pool_mean<<<NG, 256, 0, stream>>>(A1, start, pool);
  k_head1<<<NG, 128, 0, stream>>>(pool, W3, b3, g1);
  k_head2<<<NG, 64, 0, stream>>>(g1, W4, b4, out);
}

// Round 3
// 582.410 us; speedup vs baseline: 1.7233x; 1.2616x over previous
//
#include <hip/hip_runtime.h>

#define NN 100000
#define EE 1600000
#define CH 128
#define NG 512
#define OC 64

// workspace element offsets (4-byte units)
#define O_DINV   0
#define O_DEG    100096
#define O_ROWS   200128
#define O_CURS   300160
#define O_PART   400192
#define O_OFFS   400320
#define O_CSR    400448
#define O_HS     2000448   // bf16 Hs: NN*CH ushorts = 6.4M floats used
#define O_A1     14800448
#define O_START  27600448
#define O_POOL   27601024
#define O_G1     27666560

static __device__ __forceinline__ unsigned short f2bf(float x) {
  unsigned u = __float_as_uint(x);
  return (unsigned short)((u + 0x7FFFu + ((u >> 16) & 1u)) >> 16);  // RNE
}
static __device__ __forceinline__ unsigned pack2(float a, float b) {
  return (unsigned)f2bf(a) | ((unsigned)f2bf(b) << 16);
}
static __device__ __forceinline__ float bflo(unsigned v) {
  return __uint_as_float(v << 16);
}
static __device__ __forceinline__ float bfhi(unsigned v) {
  return __uint_as_float(v & 0xFFFF0000u);
}

__global__ void k_deg(const int* __restrict__ dst, int* __restrict__ deg) {
  int e = blockIdx.x * 256 + threadIdx.x;
  if (e < EE) atomicAdd(&deg[dst[e]], 1);
}

__global__ void k_dinv(const int* __restrict__ deg, float* __restrict__ dinv) {
  int i = blockIdx.x * 256 + threadIdx.x;
  if (i < NN) dinv[i] = rsqrtf((float)(deg[i] + 1));  // +1 self-loop
}

__global__ __launch_bounds__(1024) void k_scan_block(const int* __restrict__ deg,
                                                     int* __restrict__ rows,
                                                     int* __restrict__ part) {
  __shared__ int s[1024];
  int t = threadIdx.x;
  int gid = blockIdx.x * 1024 + t;
  int v = (gid < NN) ? deg[gid] : 0;
  s[t] = v;
  __syncthreads();
  for (int off = 1; off < 1024; off <<= 1) {
    int u = (t >= off) ? s[t - off] : 0;
    __syncthreads();
    if (t >= off) s[t] += u;
    __syncthreads();
  }
  if (gid < NN) rows[gid] = s[t] - v;       // exclusive
  if (t == 1023) part[blockIdx.x] = s[t];   // block total
}

__global__ void k_scan_part(const int* __restrict__ part, int* __restrict__ offs) {
  __shared__ int s[128];
  int t = threadIdx.x;
  int v = (t < 98) ? part[t] : 0;
  s[t] = v;
  __syncthreads();
  for (int off = 1; off < 128; off <<= 1) {
    int u = (t >= off) ? s[t - off] : 0;
    __syncthreads();
    if (t >= off) s[t] += u;
    __syncthreads();
  }
  if (t < 98) offs[t] = s[t] - v;
}

__global__ void k_scan_add(int* __restrict__ rows, const int* __restrict__ offs) {
  int i = blockIdx.x * 256 + threadIdx.x;
  if (i < NN) rows[i] += offs[i >> 10];
  if (i == 0) rows[NN] = EE;
}

__global__ void k_fill(const int* __restrict__ src, const int* __restrict__ dst,
                       const int* __restrict__ rows, int* __restrict__ curs,
                       int* __restrict__ csr) {
  int e = blockIdx.x * 256 + threadIdx.x;
  if (e < EE) {
    int d = dst[e];
    int pos = atomicAdd(&curs[d], 1);
    csr[rows[d] + pos] = src[e];
  }
}

// Hs(bf16) = diag(dinv) * (X @ W).  64-row tile, 256 threads, 4x8 register tile.
__global__ __launch_bounds__(256) void k_gemm_scale(
    const float* __restrict__ X, const float* __restrict__ W,
    const float* __restrict__ dinv, unsigned short* __restrict__ Hs) {
  __shared__ float Xs[64][36];
  __shared__ float Ws[32][128];
  const int t = threadIdx.x;
  const int tx = t & 15;
  const int ty = t >> 4;
  const int row0 = blockIdx.x * 64;
  float acc[4][8];
#pragma unroll
  for (int i = 0; i < 4; ++i)
#pragma unroll
    for (int j = 0; j < 8; ++j) acc[i][j] = 0.f;

  const int lr = t >> 2;
  const int lk = (t & 3) * 8;
  const int wk = t >> 5;
  const int wc = (t & 31) * 4;

  for (int kc = 0; kc < 128; kc += 32) {
    if (row0 + lr < NN) {
      const float* xp = X + (size_t)(row0 + lr) * CH + kc + lk;
      *(float4*)&Xs[lr][lk] = *(const float4*)xp;
      *(float4*)&Xs[lr][lk + 4] = *(const float4*)(xp + 4);
    } else {
      float4 z = {0.f, 0.f, 0.f, 0.f};
      *(float4*)&Xs[lr][lk] = z;
      *(float4*)&Xs[lr][lk + 4] = z;
    }
#pragma unroll
    for (int i = 0; i < 4; ++i)
      *(float4*)&Ws[wk + 8 * i][wc] =
          *(const float4*)(W + (size_t)(kc + wk + 8 * i) * CH + wc);
    __syncthreads();
#pragma unroll
    for (int k = 0; k < 32; ++k) {
      float4 w0 = *(float4*)&Ws[k][tx * 8];
      float4 w1 = *(float4*)&Ws[k][tx * 8 + 4];
#pragma unroll
      for (int i = 0; i < 4; ++i) {
        float xv = Xs[ty * 4 + i][k];
        acc[i][0] += xv * w0.x; acc[i][1] += xv * w0.y;
        acc[i][2] += xv * w0.z; acc[i][3] += xv * w0.w;
        acc[i][4] += xv * w1.x; acc[i][5] += xv * w1.y;
        acc[i][6] += xv * w1.z; acc[i][7] += xv * w1.w;
      }
    }
    __syncthreads();
  }
#pragma unroll
  for (int i = 0; i < 4; ++i) {
    int r = row0 + ty * 4 + i;
    if (r < NN) {
      float d = dinv[r];
      uint4 u;
      u.x = pack2(d * acc[i][0], d * acc[i][1]);
      u.y = pack2(d * acc[i][2], d * acc[i][3]);
      u.z = pack2(d * acc[i][4], d * acc[i][5]);
      u.w = pack2(d * acc[i][6], d * acc[i][7]);
      *(uint4*)&Hs[(size_t)r * CH + tx * 8] = u;
    }
  }
}

// out[i] = relu(dinv[i]*(Hs[i] + sum_{e:dst=i} Hs[csr[e]]) + b). One wave per node.
// H is bf16x2 rows (64 uints/row); fp32 accumulate; 4-way edge unroll for MLP.
__global__ __launch_bounds__(256) void k_aggregate(
    const unsigned* __restrict__ H, const int* __restrict__ rows,
    const int* __restrict__ csr, const float* __restrict__ dinv,
    const float* __restrict__ bias, float* __restrict__ out) {
  int node = blockIdx.x * 4 + (threadIdx.x >> 6);
  int lane = threadIdx.x & 63;
  if (node >= NN) return;
  unsigned sv = H[(size_t)node * 64 + lane];  // self-loop term
  float ax = bflo(sv), ay = bfhi(sv);
  int e = rows[node], e1 = rows[node + 1];
  for (; e + 4 <= e1; e += 4) {
    int j0 = csr[e], j1 = csr[e + 1], j2 = csr[e + 2], j3 = csr[e + 3];
    unsigned v0 = H[(size_t)j0 * 64 + lane];
    unsigned v1 = H[(size_t)j1 * 64 + lane];
    unsigned v2 = H[(size_t)j2 * 64 + lane];
    unsigned v3 = H[(size_t)j3 * 64 + lane];
    ax += bflo(v0) + bflo(v1) + bflo(v2) + bflo(v3);
    ay += bfhi(v0) + bfhi(v1) + bfhi(v2) + bfhi(v3);
  }
  for (; e < e1; ++e) {
    unsigned v = H[(size_t)csr[e] * 64 + lane];
    ax += bflo(v);
    ay += bfhi(v);
  }
  float d = dinv[node];
  float bx = bias[2 * lane], by = bias[2 * lane + 1];
  float2 o;
  o.x = fmaxf(fmaf(d, ax, bx), 0.f);
  o.y = fmaxf(fmaf(d, ay, by), 0.f);
  ((float2*)out)[(size_t)node * 64 + lane] = o;
}

// batch is sorted: graph g occupies nodes [start[g], start[g+1]).
__global__ void k_starts(const int* __restrict__ batch, int* __restrict__ start) {
  int i = blockIdx.x * 256 + threadIdx.x;
  if (i >= NN) return;
  int b = batch[i];
  int prev = (i == 0) ? -1 : batch[i - 1];
  for (int g = prev + 1; g <= b; ++g) start[g] = i;
  if (i == NN - 1)
    for (int g = b + 1; g <= NG; ++g) start[g] = NN;
}

// one block (2 waves) per graph: segmented mean, no atomics.
__global__ __launch_bounds__(256) void k_pool_mean(
    const float* __restrict__ A, const int* __restrict__ start,
    float* __restrict__ pooled) {
  __shared__ float part[128];
  int g = blockIdx.x;
  int c = threadIdx.x & 127;
  int half = threadIdx.x >> 7;
  int s0 = start[g], s1 = start[g + 1];
  float sum = 0.f;
  for (int i = s0 + half; i < s1; i += 2)
    sum += A[(size_t)i * CH + c];
  if (half) part[c] = sum;
  __syncthreads();
  if (!half) {
    sum += part[c];
    float n = fmaxf((float)(s1 - s0), 1.0f);
    pooled[(size_t)g * CH + c] = sum / n;
  }
}

__global__ void k_head1(const float* __restrict__ pooled,
                        const float* __restrict__ W3, const float* __restrict__ b3,
                        float* __restrict__ g1) {
  __shared__ float row[128];
  int g = blockIdx.x, c = threadIdx.x;
  row[c] = pooled[(size_t)g * CH + c];
  __syncthreads();
  float acc = b3[c];
  for (int k = 0; k < 128; ++k) acc += row[k] * W3[(size_t)k * CH + c];
  g1[(size_t)g * CH + c] = fmaxf(acc, 0.f);
}

__global__ void k_head2(const float* __restrict__ g1, const float* __restrict__ W4,
                        const float* __restrict__ b4, float* __restrict__ out) {
  __shared__ float row[128];
  int g = blockIdx.x, c = threadIdx.x;  // 64 threads
  row[c] = g1[(size_t)g * CH + c];
  row[c + 64] = g1[(size_t)g * CH + c + 64];
  __syncthreads();
  float acc = b4[c];
  for (int k = 0; k < 128; ++k) acc += row[k] * W4[(size_t)k * OC + c];
  out[(size_t)g * OC + c] = acc;
}

extern "C" void kernel_launch(void* const* d_in, const int* in_sizes, int n_in,
                              void* d_out, int out_size, void* d_ws, size_t ws_size,
                              hipStream_t stream) {
  const float* X   = (const float*)d_in[0];
  const int* ei    = (const int*)d_in[1];
  const int* batch = (const int*)d_in[2];
  const float* W1  = (const float*)d_in[3];
  const float* b1  = (const float*)d_in[4];
  const float* W2  = (const float*)d_in[5];
  const float* b2  = (const float*)d_in[6];
  const float* W3  = (const float*)d_in[7];
  const float* b3  = (const float*)d_in[8];
  const float* W4  = (const float*)d_in[9];
  const float* b4  = (const float*)d_in[10];
  float* out = (float*)d_out;
  float* ws = (float*)d_ws;

  const int* src = ei;        // edge_index[0]
  const int* dst = ei + EE;   // edge_index[1]

  float* dinv = ws + O_DINV;
  int* deg    = (int*)(ws + O_DEG);
  int* rows   = (int*)(ws + O_ROWS);
  int* curs   = (int*)(ws + O_CURS);
  int* part   = (int*)(ws + O_PART);
  int* offs   = (int*)(ws + O_OFFS);
  int* csr    = (int*)(ws + O_CSR);
  unsigned short* Hs = (unsigned short*)(ws + O_HS);
  float* A1   = ws + O_A1;
  int* start  = (int*)(ws + O_START);
  float* pool = ws + O_POOL;
  float* g1   = ws + O_G1;

  hipMemsetAsync(deg, 0, NN * sizeof(int), stream);
  hipMemsetAsync(curs, 0, NN * sizeof(int), stream);

  k_deg<<<(EE + 255) / 256, 256, 0, stream>>>(dst, deg);
  k_dinv<<<(NN + 255) / 256, 256, 0, stream>>>(deg, dinv);
  k_scan_block<<<98, 1024, 0, stream>>>(deg, rows, part);
  k_scan_part<<<1, 128, 0, stream>>>(part, offs);
  k_scan_add<<<(NN + 255) / 256, 256, 0, stream>>>(rows, offs);
  k_fill<<<(EE + 255) / 256, 256, 0, stream>>>(src, dst, rows, curs, csr);
  k_starts<<<(NN + 255) / 256, 256, 0, stream>>>(batch, start);

  // layer 1
  k_gemm_scale<<<(NN + 63) / 64, 256, 0, stream>>>(X, W1, dinv, Hs);
  k_aggregate<<<(NN + 3) / 4, 256, 0, stream>>>((const unsigned*)Hs, rows, csr, dinv, b1, A1);
  // layer 2
  k_gemm_scale<<<(NN + 63) / 64, 256, 0, stream>>>(A1, W2, dinv, Hs);
  k_aggregate<<<(NN + 3) / 4, 256, 0, stream>>>((const unsigned*)Hs, rows, csr, dinv, b2, A1);

  k_pool_mean<<<NG, 256, 0, stream>>>(A1, start, pool);
  k_head1<<<NG, 128, 0, stream>>>(pool, W3, b3, g1);
  k_head2<<<NG, 64, 0, stream>>>(g1, W4, b4, out);
}